// Round 15
// baseline (93.435 us; speedup 1.0000x reference)
//
#include <hip/hip_runtime.h>
#include <hip/hip_bf16.h>

// out = bias + sum_i sum_m quadratic forms (K_m folded into quad stage).
// accum: per edge, c'[m][n] += T_m * R_n  (rank-1 outer product).
//   Lane<54 owns slots (m, nb) and (m, nb+6), m=lane/6, nb=lane%6 ->
//   per edge: 1 ds_read2 (R pair, 24B apart) + 1 ds_read (T) + 2 fma.
// c2 layout: c2[atom][slot], slot = m*36 + a*12 + n  (bf16, 324/atom)
// bucket: XCD-sharded. shard = blockIdx&7 (round-robin dispatch -> XCD).
//   cnt[shard*N + i], bucket[(shard*N + i)*16 + p] (u16), cap 16/shard.

#define NT 3
#define CPA 324
#define A_ELEMS 3888
#define SCAP 16
#define WPB 4        // waves per block in accum
#define RSTRIDE 25   // record stride in floats (odd -> conflict-free)

typedef __attribute__((ext_vector_type(4))) unsigned short ushort4v;
typedef unsigned long long ull;

#if __has_builtin(__builtin_amdgcn_exp2f)
__device__ __forceinline__ float exp2_fast(float x) { return __builtin_amdgcn_exp2f(x); }
#else
__device__ __forceinline__ float exp2_fast(float x) { return __expf(x * 0.6931471805599453f); }
#endif

__global__ void prep_kernel(const float* __restrict__ w,
                            const float* __restrict__ bias,
                            const float* __restrict__ pos,
                            const int* __restrict__ types,
                            float* __restrict__ A,
                            float4* __restrict__ posT,
                            float* __restrict__ out, int N) {
    int t = blockIdx.x * blockDim.x + threadIdx.x;
    if (t == 0) out[0] = bias[0];
    if (t < A_ELEMS) {
        int l   = t / 1296;
        int rem = t - l * 1296;
        int an  = rem / 36;
        int bk  = rem - an * 36;
        int a = an / 12, n = an - (an / 12) * 12;
        int b = bk / 12, k = bk - (bk / 12) * 12;
        float inv = (l == 0) ? 1.0f : (l == 1 ? 0.57735026918962576f
                                              : 0.44721359549995794f);
        A[t] = w[a * 1296 + n * 108 + b * 36 + k * 3 + l] * inv;
    }
    if (t < N) {
        float4 p;
        p.x = pos[3 * t + 0];
        p.y = pos[3 * t + 1];
        p.z = pos[3 * t + 2];
        p.w = __int_as_float(types[t]);
        posT[t] = p;
    }
}

__device__ __forceinline__ void build_one(int i, int j, int shard, int N,
                                          const float4& a, const float4& b,
                                          int* cnt, unsigned short* bucket) {
    float dx = b.x - a.x, dy = b.y - a.y, dz = b.z - a.z;
    float r2 = dx * dx + dy * dy + dz * dz;
    if (r2 < 12.96f) {
        int idx = shard * N + i;
        int p = atomicAdd(&cnt[idx], 1);
        if (p < SCAP) bucket[(idx << 4) + p] = (unsigned short)j;
    }
}

// Filtered sharded build; 4 edges/thread, gathers batched for MLP.
__global__ void build_kernel(const int* __restrict__ pairs,
                             const float4* __restrict__ posT,
                             int* __restrict__ cnt,
                             unsigned short* __restrict__ bucket,
                             int E, int N) {
    int shard = blockIdx.x & 7;              // round-robin dispatch -> XCD id
    int t = blockIdx.x * blockDim.x + threadIdx.x;
    int e0 = t << 2;
    if (e0 >= E) return;
    if (e0 + 4 <= E) {
        int4 q0 = ((const int4*)pairs)[t * 2];
        int4 q1 = ((const int4*)pairs)[t * 2 + 1];
        float4 a0 = posT[q0.x], b0 = posT[q0.y];
        float4 a1 = posT[q0.z], b1 = posT[q0.w];
        float4 a2 = posT[q1.x], b2 = posT[q1.y];
        float4 a3 = posT[q1.z], b3 = posT[q1.w];
        build_one(q0.x, q0.y, shard, N, a0, b0, cnt, bucket);
        build_one(q0.z, q0.w, shard, N, a1, b1, cnt, bucket);
        build_one(q1.x, q1.y, shard, N, a2, b2, cnt, bucket);
        build_one(q1.z, q1.w, shard, N, a3, b3, cnt, bucket);
    } else {
        for (int e = e0; e < E; ++e) {
            int i = pairs[2 * e], j = pairs[2 * e + 1];
            float4 a = posT[i], b = posT[j];
            build_one(i, j, shard, N, a, b, cnt, bucket);
        }
    }
}

// One wave per atom. Prologue: lane -> (shard, offset) via 8 counters +
// prefix cascade, gather neighbor, compute R[0..11] (12 exp2) + T[0..8],
// type-sort via ballots, write 21-float record at stride 25. Edge loop:
// ds_read2(R,R+6) + ds_read(T) + 2 fma per edge.
__global__ void __launch_bounds__(256)
accum_kernel(const float4* __restrict__ posT,
             const int* __restrict__ cnt,
             const unsigned short* __restrict__ bucket,
             __hip_bfloat16* __restrict__ c2, int N) {
    __shared__ float sE[WPB][64][RSTRIDE];
    int wid = (blockIdx.x * blockDim.x + threadIdx.x) >> 6;
    int lane = threadIdx.x & 63;
    int wslot = (threadIdx.x >> 6);
    if (wid >= N) return;
    int i = wid;

    float4 pi = posT[i];

    int d0 = min(cnt[0 * N + i], SCAP);
    int d1 = min(cnt[1 * N + i], SCAP);
    int d2 = min(cnt[2 * N + i], SCAP);
    int d3 = min(cnt[3 * N + i], SCAP);
    int d4 = min(cnt[4 * N + i], SCAP);
    int d5 = min(cnt[5 * N + i], SCAP);
    int d6 = min(cnt[6 * N + i], SCAP);
    int d7 = min(cnt[7 * N + i], SCAP);
    int p1 = d0, p2 = p1 + d1, p3 = p2 + d2, p4 = p3 + d3;
    int p5 = p4 + d4, p6 = p5 + d5, p7 = p6 + d6;
    int tot = p7 + d7;
    int deg = __builtin_amdgcn_readfirstlane(min(tot, 64));

    int k = lane;
    int seg = (k >= p1) + (k >= p2) + (k >= p3) + (k >= p4)
            + (k >= p5) + (k >= p6) + (k >= p7);
    int bs = 0;
    bs = (seg >= 1) ? p1 : bs;  bs = (seg >= 2) ? p2 : bs;
    bs = (seg >= 3) ? p3 : bs;  bs = (seg >= 4) ? p4 : bs;
    bs = (seg >= 5) ? p5 : bs;  bs = (seg >= 6) ? p6 : bs;
    bs = (seg >= 7) ? p7 : bs;
    int off = (k - bs) & (SCAP - 1);
    int jv = bucket[((seg * N + i) << 4) + off];

    bool valid = lane < deg;
    int jsafe = valid ? jv : i;
    float4 pj = posT[jsafe];

    float dx = pj.x - pi.x, dy = pj.y - pi.y, dz = pj.z - pi.z;
    float u  = fmaf(dz, dz, fmaf(dy, dy, fmaf(dx, dx, 1e-12f)));
    float wv = __log2f(u);
    float ir = rsqrtf(u);
    float iu = ir * ir;
    float lf = 0.0f;
    if (u >= 10.89f) {                       // 3.3 <= r < 3.6: taper into exp
        float r = sqrtf(u);
        float fcv = 0.5f + 0.5f * __cosf(10.471975511965978f * (r - 3.3f));
        lf = __log2f(fcv);
    }
    int tj = __float_as_int(pj.w);

    // 12 radials R_n = exp2(0.5n*log2(u) + qc_n*u + lf)
    const float QC[12] = {
        -8.014972449383130f, -8.014972449383130f, -4.007486224691565f,
        -2.671657483127710f, -2.003743112345783f, -1.602994489876626f,
        -1.335828741563855f, -1.144996064197590f, -1.001871556172891f,
        -0.890552494375903f, -0.801497244938313f, -0.728633859034830f };
    float R[12];
    #pragma unroll
    for (int n = 0; n < 12; ++n)
        R[n] = exp2_fast(fmaf(0.5f * n, wv, fmaf(QC[n], u, lf)));

    // type-sort among valid lanes
    ull m0b = __ballot(valid && tj == 0);
    ull m1b = __ballot(valid && tj == 1);
    ull m2b = __ballot(valid && tj == 2);
    ull lt  = (lane == 63) ? 0x7FFFFFFFFFFFFFFFull : ((1ull << lane) - 1ull);
    int c0n = __popcll(m0b);
    int c1n = __popcll(m1b);
    int dest;
    if (!valid)          dest = deg + __popcll(~(m0b | m1b | m2b) & lt);
    else if (tj == 0)    dest = __popcll(m0b & lt);
    else if (tj == 1)    dest = c0n + __popcll(m1b & lt);
    else                 dest = c0n + c1n + __popcll(m2b & lt);

    float* rec = &sE[wslot][dest][0];
    #pragma unroll
    for (int n = 0; n < 12; ++n) rec[n] = R[n];
    rec[12] = 1.0f;
    rec[13] = dy * ir;  rec[14] = dz * ir;  rec[15] = dx * ir;
    rec[16] = dx * dy * iu;
    rec[17] = dy * dz * iu;
    rec[18] = fmaf(dz, dz, -0.33333333333333333f * u) * iu;
    rec[19] = dx * dz * iu;
    rec[20] = fmaf(dx, dx, -(dy * dy)) * iu;
    asm volatile("s_waitcnt lgkmcnt(0)" ::: "memory");

    int e1b = c0n + c1n;                     // scalar (ballot popcounts)

    // same-m slot pairing: lane<54 owns (m0, nb) and (m0, nb+6)
    bool active = lane < 54;
    int m0 = active ? (lane / 6) : 0;
    int nb = active ? (lane - (lane / 6) * 6) : 0;

    const float* recb = &sE[wslot][0][0];

    float a00 = 0.f, a01 = 0.f, a02 = 0.f;   // slot (m0,nb)    x 3 types
    float a10 = 0.f, a11 = 0.f, a12 = 0.f;   // slot (m0,nb+6)  x 3 types

    #define EDGE_BODY(E_IDX, ACC0, ACC1)                                   \
    {                                                                      \
        const float* rp  = recb + (E_IDX) * RSTRIDE;                       \
        const float* rpn = rp + nb;                                        \
        float Rlo = rpn[0];                                                \
        float Rhi = rpn[6];                                                \
        float Tv  = rp[12 + m0];                                           \
        ACC0 = fmaf(Rlo, Tv, ACC0);                                        \
        ACC1 = fmaf(Rhi, Tv, ACC1);                                        \
    }

    int e = 0;
    #pragma unroll 2
    for (; e < c0n; ++e)  EDGE_BODY(e, a00, a10);
    #pragma unroll 2
    for (; e < e1b; ++e)  EDGE_BODY(e, a01, a11);
    #pragma unroll 2
    for (; e < deg; ++e)  EDGE_BODY(e, a02, a12);
    #undef EDGE_BODY

    if (active) {
        __hip_bfloat16* cb = c2 + (size_t)i * CPA + m0 * 36;
        cb[0 * 12 + nb]     = __float2bfloat16(a00);
        cb[1 * 12 + nb]     = __float2bfloat16(a01);
        cb[2 * 12 + nb]     = __float2bfloat16(a02);
        cb[0 * 12 + nb + 6] = __float2bfloat16(a10);
        cb[1 * 12 + nb + 6] = __float2bfloat16(a11);
        cb[2 * 12 + nb + 6] = __float2bfloat16(a12);
    }
}

// Wave = (64 atoms, one m). Rescale v by K_m, add Y00 self-term, v^T A_l v.
__global__ void __launch_bounds__(576)
quad_kernel(const __hip_bfloat16* __restrict__ c2,
            const int* __restrict__ types,
            const float* __restrict__ A,
            float* __restrict__ out, int N) {
    __shared__ float sred[9];
    int m = __builtin_amdgcn_readfirstlane(threadIdx.x >> 6);
    int lane = threadIdx.x & 63;
    int i = blockIdx.x * 64 + lane;
    float dot = 0.0f;
    if (i < N) {
        float Km = m == 0 ? 0.28209479177387814f
                 : (m < 4 ? 0.4886025119029199f
                 : (m == 6 ? 0.94617469575756f
                 : (m == 8 ? 0.5462742152960396f : 1.0925484305920792f)));
        const ushort4v* cb4 =
            (const ushort4v*)(c2 + (size_t)i * CPA + m * 36);
        float v[36];
        #pragma unroll
        for (int q = 0; q < 9; ++q) {
            ushort4v u = cb4[q];
            #pragma unroll
            for (int r = 0; r < 4; ++r)
                v[q * 4 + r] = __uint_as_float(((unsigned)u[r]) << 16) * Km;
        }
        if (m == 0) {
            int ti = types[i];
            const float Y00 = 0.28209479177387814f;
            v[0]  += ti == 0 ? Y00 : 0.f;
            v[12] += ti == 1 ? Y00 : 0.f;
            v[24] += ti == 2 ? Y00 : 0.f;
        }
        int l = (m == 0) ? 0 : (m < 4 ? 1 : 2);
        const float* Al = A + l * 1296;
        #pragma unroll
        for (int an = 0; an < 36; ++an) {
            float s = 0.0f;
            #pragma unroll
            for (int b = 0; b < 36; ++b)
                s = fmaf(Al[an * 36 + b], v[b], s);
            dot = fmaf(v[an], s, dot);
        }
    }
    #pragma unroll
    for (int off = 32; off > 0; off >>= 1) dot += __shfl_down(dot, off, 64);
    if (lane == 0) sred[m] = dot;
    __syncthreads();
    if (threadIdx.x == 0) {
        float s = 0.f;
        #pragma unroll
        for (int kk = 0; kk < 9; ++kk) s += sred[kk];
        atomicAdd(out, s);
    }
}

extern "C" void kernel_launch(void* const* d_in, const int* in_sizes, int n_in,
                              void* d_out, int out_size, void* d_ws, size_t ws_size,
                              hipStream_t stream) {
    const float* pos   = (const float*)d_in[0];
    const float* w     = (const float*)d_in[1];
    const float* bias  = (const float*)d_in[2];
    const int*   types = (const int*)d_in[3];
    const int*   pairs = (const int*)d_in[4];
    float* out = (float*)d_out;

    int N = in_sizes[0] / 3;
    int E = in_sizes[4] / 2;

    char* ws = (char*)d_ws;
    size_t off = 0;
    float* A = (float*)(ws + off);             off += 16384;
    int* cnt = (int*)(ws + off);               off += ((size_t)N * 32 + 255) & ~(size_t)255;   // 8N ints
    float4* posT = (float4*)(ws + off);        off += ((size_t)N * 16 + 255) & ~(size_t)255;
    unsigned short* bucket = (unsigned short*)(ws + off);
                                               off += ((size_t)N * 8 * SCAP * 2 + 255) & ~(size_t)255;
    __hip_bfloat16* c2 = (__hip_bfloat16*)(ws + off);

    hipMemsetAsync(cnt, 0, (size_t)N * 32, stream);

    int pblocks = (N + 255) / 256;
    prep_kernel<<<pblocks, 256, 0, stream>>>(w, bias, pos, types, A, posT, out, N);

    int equads = (E + 3) / 4;
    int eblocks = (equads + 255) / 256;
    build_kernel<<<eblocks, 256, 0, stream>>>(pairs, posT, cnt, bucket, E, N);

    int ablocks = ((size_t)N * 64 + 255) / 256;
    accum_kernel<<<ablocks, 256, 0, stream>>>(posT, cnt, bucket, c2, N);

    int qblocks = (N + 63) / 64;
    quad_kernel<<<qblocks, 576, 0, stream>>>(c2, types, A, out, N);
}

// Round 16
// 91.810 us; speedup vs baseline: 1.0177x; 1.0177x over previous
//
#include <hip/hip_runtime.h>
#include <hip/hip_bf16.h>

// out = bias + sum_i sum_m quadratic forms (K_m folded into quad stage).
// accum: per edge, c'[m][n] += T_m * R_n  (rank-1 outer product).
// c2 layout: c2[atom][slot], slot = m*36 + a*12 + n  (bf16, 324/atom)
// bucket: XCD-sharded. shard = blockIdx&7 (round-robin dispatch -> XCD).
// accum blocks are tile-swizzled so 64-atom tile t runs on XCD t%8 --
// matching quad's block q -> XCD q%8 -> tile q. c2 stays XCD-local in L2.

#define NT 3
#define CPA 324
#define A_ELEMS 3888
#define SCAP 16
#define WPB 4        // waves per block in accum
#define RSTRIDE 25   // record stride in floats (odd -> conflict-free)

typedef __attribute__((ext_vector_type(4))) unsigned short ushort4v;
typedef unsigned long long ull;

#if __has_builtin(__builtin_amdgcn_exp2f)
__device__ __forceinline__ float exp2_fast(float x) { return __builtin_amdgcn_exp2f(x); }
#else
__device__ __forceinline__ float exp2_fast(float x) { return __expf(x * 0.6931471805599453f); }
#endif

__global__ void prep_kernel(const float* __restrict__ w,
                            const float* __restrict__ bias,
                            const float* __restrict__ pos,
                            const int* __restrict__ types,
                            float* __restrict__ A,
                            float4* __restrict__ posT,
                            int* __restrict__ cnt,      // 8N ints
                            float* __restrict__ out, int N) {
    int t = blockIdx.x * blockDim.x + threadIdx.x;
    if (t == 0) out[0] = bias[0];
    if (t < A_ELEMS) {
        int l   = t / 1296;
        int rem = t - l * 1296;
        int an  = rem / 36;
        int bk  = rem - an * 36;
        int a = an / 12, n = an - (an / 12) * 12;
        int b = bk / 12, k = bk - (bk / 12) * 12;
        float inv = (l == 0) ? 1.0f : (l == 1 ? 0.57735026918962576f
                                              : 0.44721359549995794f);
        A[t] = w[a * 1296 + n * 108 + b * 36 + k * 3 + l] * inv;
    }
    if (t < N) {
        float4 p;
        p.x = pos[3 * t + 0];
        p.y = pos[3 * t + 1];
        p.z = pos[3 * t + 2];
        p.w = __int_as_float(types[t]);
        posT[t] = p;
    }
    if (t < 8 * N) cnt[t] = 0;
}

__device__ __forceinline__ void build_one(int i, int j, int shard, int N,
                                          const float4& a, const float4& b,
                                          int* cnt, unsigned short* bucket) {
    float dx = b.x - a.x, dy = b.y - a.y, dz = b.z - a.z;
    float r2 = dx * dx + dy * dy + dz * dz;
    if (r2 < 12.96f) {
        int idx = shard * N + i;
        int p = atomicAdd(&cnt[idx], 1);
        if (p < SCAP) bucket[(idx << 4) + p] = (unsigned short)j;
    }
}

// Filtered sharded build; 4 edges/thread, gathers batched for MLP.
__global__ void build_kernel(const int* __restrict__ pairs,
                             const float4* __restrict__ posT,
                             int* __restrict__ cnt,
                             unsigned short* __restrict__ bucket,
                             int E, int N) {
    int shard = blockIdx.x & 7;              // round-robin dispatch -> XCD id
    int t = blockIdx.x * blockDim.x + threadIdx.x;
    int e0 = t << 2;
    if (e0 >= E) return;
    if (e0 + 4 <= E) {
        int4 q0 = ((const int4*)pairs)[t * 2];
        int4 q1 = ((const int4*)pairs)[t * 2 + 1];
        float4 a0 = posT[q0.x], b0 = posT[q0.y];
        float4 a1 = posT[q0.z], b1 = posT[q0.w];
        float4 a2 = posT[q1.x], b2 = posT[q1.y];
        float4 a3 = posT[q1.z], b3 = posT[q1.w];
        build_one(q0.x, q0.y, shard, N, a0, b0, cnt, bucket);
        build_one(q0.z, q0.w, shard, N, a1, b1, cnt, bucket);
        build_one(q1.x, q1.y, shard, N, a2, b2, cnt, bucket);
        build_one(q1.z, q1.w, shard, N, a3, b3, cnt, bucket);
    } else {
        for (int e = e0; e < E; ++e) {
            int i = pairs[2 * e], j = pairs[2 * e + 1];
            float4 a = posT[i], b = posT[j];
            build_one(i, j, shard, N, a, b, cnt, bucket);
        }
    }
}

// One wave per atom. Tile-swizzled: block k -> x=k&7, idx=k>>3, tile
// t = (idx>>4)*8 + x, sub-block b = idx&15 -> atoms t*64 + b*4 + wave.
// Prologue: lane -> (shard, offset) via 8 counters + prefix cascade, gather
// neighbor, compute R[0..11] (12 exp2) + T[0..8], type-sort via ballots,
// write 21-float record at stride 25. Edge loop: 4 ds_read + 2 fma / edge.
__global__ void __launch_bounds__(256)
accum_kernel(const float4* __restrict__ posT,
             const int* __restrict__ cnt,
             const unsigned short* __restrict__ bucket,
             __hip_bfloat16* __restrict__ c2, int N, int T) {
    __shared__ float sE[WPB][64][RSTRIDE];
    int k = blockIdx.x;
    int x = k & 7;
    int idx = k >> 3;
    int t = (idx >> 4) * 8 + x;
    if (t >= T) return;
    int lane = threadIdx.x & 63;
    int wslot = (threadIdx.x >> 6);
    int i = t * 64 + (idx & 15) * 4 + wslot;
    if (i >= N) return;

    float4 pi = posT[i];

    int d0 = min(cnt[0 * N + i], SCAP);
    int d1 = min(cnt[1 * N + i], SCAP);
    int d2 = min(cnt[2 * N + i], SCAP);
    int d3 = min(cnt[3 * N + i], SCAP);
    int d4 = min(cnt[4 * N + i], SCAP);
    int d5 = min(cnt[5 * N + i], SCAP);
    int d6 = min(cnt[6 * N + i], SCAP);
    int d7 = min(cnt[7 * N + i], SCAP);
    int p1 = d0, p2 = p1 + d1, p3 = p2 + d2, p4 = p3 + d3;
    int p5 = p4 + d4, p6 = p5 + d5, p7 = p6 + d6;
    int tot = p7 + d7;
    int deg = __builtin_amdgcn_readfirstlane(min(tot, 64));

    int kk = lane;
    int seg = (kk >= p1) + (kk >= p2) + (kk >= p3) + (kk >= p4)
            + (kk >= p5) + (kk >= p6) + (kk >= p7);
    int bs = 0;
    bs = (seg >= 1) ? p1 : bs;  bs = (seg >= 2) ? p2 : bs;
    bs = (seg >= 3) ? p3 : bs;  bs = (seg >= 4) ? p4 : bs;
    bs = (seg >= 5) ? p5 : bs;  bs = (seg >= 6) ? p6 : bs;
    bs = (seg >= 7) ? p7 : bs;
    int off = (kk - bs) & (SCAP - 1);
    int jv = bucket[((seg * N + i) << 4) + off];

    bool valid = lane < deg;
    int jsafe = valid ? jv : i;
    float4 pj = posT[jsafe];

    float dx = pj.x - pi.x, dy = pj.y - pi.y, dz = pj.z - pi.z;
    float u  = fmaf(dz, dz, fmaf(dy, dy, fmaf(dx, dx, 1e-12f)));
    float wv = __log2f(u);
    float ir = rsqrtf(u);
    float iu = ir * ir;
    float lf = 0.0f;
    if (u >= 10.89f) {                       // 3.3 <= r < 3.6: taper into exp
        float r = sqrtf(u);
        float fcv = 0.5f + 0.5f * __cosf(10.471975511965978f * (r - 3.3f));
        lf = __log2f(fcv);
    }
    int tj = __float_as_int(pj.w);

    // 12 radials R_n = exp2(0.5n*log2(u) + qc_n*u + lf)
    const float QC[12] = {
        -8.014972449383130f, -8.014972449383130f, -4.007486224691565f,
        -2.671657483127710f, -2.003743112345783f, -1.602994489876626f,
        -1.335828741563855f, -1.144996064197590f, -1.001871556172891f,
        -0.890552494375903f, -0.801497244938313f, -0.728633859034830f };
    float R[12];
    #pragma unroll
    for (int n = 0; n < 12; ++n)
        R[n] = exp2_fast(fmaf(0.5f * n, wv, fmaf(QC[n], u, lf)));

    // type-sort among valid lanes
    ull m0b = __ballot(valid && tj == 0);
    ull m1b = __ballot(valid && tj == 1);
    ull m2b = __ballot(valid && tj == 2);
    ull lt  = (lane == 63) ? 0x7FFFFFFFFFFFFFFFull : ((1ull << lane) - 1ull);
    int c0n = __popcll(m0b);
    int c1n = __popcll(m1b);
    int dest;
    if (!valid)          dest = deg + __popcll(~(m0b | m1b | m2b) & lt);
    else if (tj == 0)    dest = __popcll(m0b & lt);
    else if (tj == 1)    dest = c0n + __popcll(m1b & lt);
    else                 dest = c0n + c1n + __popcll(m2b & lt);

    float* rec = &sE[wslot][dest][0];
    #pragma unroll
    for (int n = 0; n < 12; ++n) rec[n] = R[n];
    rec[12] = 1.0f;
    rec[13] = dy * ir;  rec[14] = dz * ir;  rec[15] = dx * ir;
    rec[16] = dx * dy * iu;
    rec[17] = dy * dz * iu;
    rec[18] = fmaf(dz, dz, -0.33333333333333333f * u) * iu;
    rec[19] = dx * dz * iu;
    rec[20] = fmaf(dx, dx, -(dy * dy)) * iu;
    asm volatile("s_waitcnt lgkmcnt(0)" ::: "memory");

    int e1b = c0n + c1n;                     // scalar (ballot popcounts)

    // per-lane slot indices: slot0 = lane, slot1 = lane+64 (slot = m*12+n)
    int n0 = lane % 12, m0 = lane / 12;
    int idx1 = lane + 64;
    bool has1 = idx1 < 108;
    int i1 = has1 ? idx1 : 0;
    int n1 = i1 % 12, m1 = i1 / 12;

    const float* recb = &sE[wslot][0][0];

    float a00 = 0.f, a01 = 0.f, a02 = 0.f;
    float a10 = 0.f, a11 = 0.f, a12 = 0.f;

    #define EDGE_BODY(E_IDX, ACC0, ACC1)                                   \
    {                                                                      \
        const float* rp = recb + (E_IDX) * RSTRIDE;                        \
        float Rv0 = rp[n0];                                                \
        float Tv0 = rp[12 + m0];                                           \
        float Rv1 = rp[n1];                                                \
        float Tv1 = rp[12 + m1];                                           \
        ACC0 = fmaf(Rv0, Tv0, ACC0);                                       \
        ACC1 = fmaf(Rv1, Tv1, ACC1);                                       \
    }

    int e = 0;
    #pragma unroll 4
    for (; e < c0n; ++e)  EDGE_BODY(e, a00, a10);
    #pragma unroll 4
    for (; e < e1b; ++e)  EDGE_BODY(e, a01, a11);
    #pragma unroll 4
    for (; e < deg; ++e)  EDGE_BODY(e, a02, a12);
    #undef EDGE_BODY

    __hip_bfloat16* cb = c2 + (size_t)i * CPA;
    cb[m0 * 36 + 0 * 12 + n0] = __float2bfloat16(a00);
    cb[m0 * 36 + 1 * 12 + n0] = __float2bfloat16(a01);
    cb[m0 * 36 + 2 * 12 + n0] = __float2bfloat16(a02);
    if (has1) {
        cb[m1 * 36 + 0 * 12 + n1] = __float2bfloat16(a10);
        cb[m1 * 36 + 1 * 12 + n1] = __float2bfloat16(a11);
        cb[m1 * 36 + 2 * 12 + n1] = __float2bfloat16(a12);
    }
}

// Wave = (64 atoms, one m). Block q = tile q -> XCD q%8 (matches accum).
__global__ void __launch_bounds__(576)
quad_kernel(const __hip_bfloat16* __restrict__ c2,
            const int* __restrict__ types,
            const float* __restrict__ A,
            float* __restrict__ out, int N) {
    __shared__ float sred[9];
    int m = __builtin_amdgcn_readfirstlane(threadIdx.x >> 6);
    int lane = threadIdx.x & 63;
    int i = blockIdx.x * 64 + lane;
    float dot = 0.0f;
    if (i < N) {
        float Km = m == 0 ? 0.28209479177387814f
                 : (m < 4 ? 0.4886025119029199f
                 : (m == 6 ? 0.94617469575756f
                 : (m == 8 ? 0.5462742152960396f : 1.0925484305920792f)));
        const ushort4v* cb4 =
            (const ushort4v*)(c2 + (size_t)i * CPA + m * 36);
        float v[36];
        #pragma unroll
        for (int q = 0; q < 9; ++q) {
            ushort4v u = cb4[q];
            #pragma unroll
            for (int r = 0; r < 4; ++r)
                v[q * 4 + r] = __uint_as_float(((unsigned)u[r]) << 16) * Km;
        }
        if (m == 0) {
            int ti = types[i];
            const float Y00 = 0.28209479177387814f;
            v[0]  += ti == 0 ? Y00 : 0.f;
            v[12] += ti == 1 ? Y00 : 0.f;
            v[24] += ti == 2 ? Y00 : 0.f;
        }
        int l = (m == 0) ? 0 : (m < 4 ? 1 : 2);
        const float* Al = A + l * 1296;
        #pragma unroll
        for (int an = 0; an < 36; ++an) {
            float s = 0.0f;
            #pragma unroll
            for (int b = 0; b < 36; ++b)
                s = fmaf(Al[an * 36 + b], v[b], s);
            dot = fmaf(v[an], s, dot);
        }
    }
    #pragma unroll
    for (int off = 32; off > 0; off >>= 1) dot += __shfl_down(dot, off, 64);
    if (lane == 0) sred[m] = dot;
    __syncthreads();
    if (threadIdx.x == 0) {
        float s = 0.f;
        #pragma unroll
        for (int kk = 0; kk < 9; ++kk) s += sred[kk];
        atomicAdd(out, s);
    }
}

extern "C" void kernel_launch(void* const* d_in, const int* in_sizes, int n_in,
                              void* d_out, int out_size, void* d_ws, size_t ws_size,
                              hipStream_t stream) {
    const float* pos   = (const float*)d_in[0];
    const float* w     = (const float*)d_in[1];
    const float* bias  = (const float*)d_in[2];
    const int*   types = (const int*)d_in[3];
    const int*   pairs = (const int*)d_in[4];
    float* out = (float*)d_out;

    int N = in_sizes[0] / 3;
    int E = in_sizes[4] / 2;

    char* ws = (char*)d_ws;
    size_t off = 0;
    float* A = (float*)(ws + off);             off += 16384;
    int* cnt = (int*)(ws + off);               off += ((size_t)N * 32 + 255) & ~(size_t)255;   // 8N ints
    float4* posT = (float4*)(ws + off);        off += ((size_t)N * 16 + 255) & ~(size_t)255;
    unsigned short* bucket = (unsigned short*)(ws + off);
                                               off += ((size_t)N * 8 * SCAP * 2 + 255) & ~(size_t)255;
    __hip_bfloat16* c2 = (__hip_bfloat16*)(ws + off);

    int pblocks = (8 * N + 255) / 256;
    prep_kernel<<<pblocks, 256, 0, stream>>>(w, bias, pos, types, A, posT, cnt, out, N);

    int equads = (E + 3) / 4;
    int eblocks = (equads + 255) / 256;
    build_kernel<<<eblocks, 256, 0, stream>>>(pairs, posT, cnt, bucket, E, N);

    int T = (N + 63) / 64;                    // 64-atom tiles
    int perXCD = (T + 7) / 8;
    int ablocks = perXCD * 8 * 16;            // 16 blocks (4 atoms each) per tile
    accum_kernel<<<ablocks, 256, 0, stream>>>(posT, cnt, bucket, c2, N, T);

    int qblocks = T;
    quad_kernel<<<qblocks, 576, 0, stream>>>(c2, types, A, out, N);
}

// Round 17
// 91.528 us; speedup vs baseline: 1.0208x; 1.0031x over previous
//
#include <hip/hip_runtime.h>
#include <hip/hip_bf16.h>

// out = bias + sum_i sum_m quadratic forms (K_m folded into quad stage).
// accum: per edge, c'[m][n] += T_m * R_n  (rank-1 outer product).
// c2 layout: c2[atom][slot], slot = m*36 + a*12 + n  (bf16, 324/atom)
// bucket: XCD-sharded EDGE RECORDS (8B: f16 dx,dy,dz + u16 type) --
//   accum needs no posT gather at all. shard = blockIdx&7 (round-robin
//   dispatch -> XCD). cnt[shard*N+i], bucket[(shard*N+i)*16+p], cap 16.

#define NT 3
#define CPA 324
#define A_ELEMS 3888
#define SCAP 16
#define WPB 4        // waves per block in accum
#define RSTRIDE 25   // record stride in floats (odd -> conflict-free)

typedef __attribute__((ext_vector_type(4))) unsigned short ushort4v;
typedef unsigned long long ull;

union EdgeRec {
    _Float16 h[4];
    unsigned short s[4];
    uint2 u;
};

#if __has_builtin(__builtin_amdgcn_exp2f)
__device__ __forceinline__ float exp2_fast(float x) { return __builtin_amdgcn_exp2f(x); }
#else
__device__ __forceinline__ float exp2_fast(float x) { return __expf(x * 0.6931471805599453f); }
#endif

__global__ void prep_kernel(const float* __restrict__ w,
                            const float* __restrict__ bias,
                            const float* __restrict__ pos,
                            const int* __restrict__ types,
                            float* __restrict__ A,
                            float4* __restrict__ posT,
                            int* __restrict__ cnt,      // 8N ints
                            float* __restrict__ out, int N) {
    int t = blockIdx.x * blockDim.x + threadIdx.x;
    if (t == 0) out[0] = bias[0];
    if (t < A_ELEMS) {
        int l   = t / 1296;
        int rem = t - l * 1296;
        int an  = rem / 36;
        int bk  = rem - an * 36;
        int a = an / 12, n = an - (an / 12) * 12;
        int b = bk / 12, k = bk - (bk / 12) * 12;
        float inv = (l == 0) ? 1.0f : (l == 1 ? 0.57735026918962576f
                                              : 0.44721359549995794f);
        A[t] = w[a * 1296 + n * 108 + b * 36 + k * 3 + l] * inv;
    }
    if (t < N) {
        float4 p;
        p.x = pos[3 * t + 0];
        p.y = pos[3 * t + 1];
        p.z = pos[3 * t + 2];
        p.w = __int_as_float(types[t]);
        posT[t] = p;
    }
    if (t < 8 * N) cnt[t] = 0;
}

__device__ __forceinline__ void build_one(int i, int j, int shard, int N,
                                          const float4& a, const float4& b,
                                          int* cnt, uint2* bucket) {
    float dx = b.x - a.x, dy = b.y - a.y, dz = b.z - a.z;
    float r2 = dx * dx + dy * dy + dz * dz;
    if (r2 < 12.96f) {
        int idx = shard * N + i;
        int p = atomicAdd(&cnt[idx], 1);
        if (p < SCAP) {
            EdgeRec r;
            r.h[0] = (_Float16)dx;
            r.h[1] = (_Float16)dy;
            r.h[2] = (_Float16)dz;
            r.s[3] = (unsigned short)__float_as_int(b.w);
            bucket[(idx << 4) + p] = r.u;
        }
    }
}

// Filtered sharded build; 8B edge records; 4 edges/thread, gathers batched.
__global__ void build_kernel(const int* __restrict__ pairs,
                             const float4* __restrict__ posT,
                             int* __restrict__ cnt,
                             uint2* __restrict__ bucket,
                             int E, int N) {
    int shard = blockIdx.x & 7;              // round-robin dispatch -> XCD id
    int t = blockIdx.x * blockDim.x + threadIdx.x;
    int e0 = t << 2;
    if (e0 >= E) return;
    if (e0 + 4 <= E) {
        int4 q0 = ((const int4*)pairs)[t * 2];
        int4 q1 = ((const int4*)pairs)[t * 2 + 1];
        float4 a0 = posT[q0.x], b0 = posT[q0.y];
        float4 a1 = posT[q0.z], b1 = posT[q0.w];
        float4 a2 = posT[q1.x], b2 = posT[q1.y];
        float4 a3 = posT[q1.z], b3 = posT[q1.w];
        build_one(q0.x, q0.y, shard, N, a0, b0, cnt, bucket);
        build_one(q0.z, q0.w, shard, N, a1, b1, cnt, bucket);
        build_one(q1.x, q1.y, shard, N, a2, b2, cnt, bucket);
        build_one(q1.z, q1.w, shard, N, a3, b3, cnt, bucket);
    } else {
        for (int e = e0; e < E; ++e) {
            int i = pairs[2 * e], j = pairs[2 * e + 1];
            float4 a = posT[i], b = posT[j];
            build_one(i, j, shard, N, a, b, cnt, bucket);
        }
    }
}

// One wave per atom (tile-swizzled to XCDs). Prologue: lane -> (shard,off)
// via 8 counters + prefix cascade, load 8B edge record (NO posT gather),
// compute R[0..11] (12 exp2) + T[0..8], type-sort via ballots, write
// 21-float record at stride 25. Edge loop: 4 ds_read + 2 fma / edge.
__global__ void __launch_bounds__(256)
accum_kernel(const int* __restrict__ cnt,
             const uint2* __restrict__ bucket,
             __hip_bfloat16* __restrict__ c2, int N, int T) {
    __shared__ float sE[WPB][64][RSTRIDE];
    int k = blockIdx.x;
    int x = k & 7;
    int idx = k >> 3;
    int t = (idx >> 4) * 8 + x;
    if (t >= T) return;
    int lane = threadIdx.x & 63;
    int wslot = (threadIdx.x >> 6);
    int i = t * 64 + (idx & 15) * 4 + wslot;
    if (i >= N) return;

    int d0 = min(cnt[0 * N + i], SCAP);
    int d1 = min(cnt[1 * N + i], SCAP);
    int d2 = min(cnt[2 * N + i], SCAP);
    int d3 = min(cnt[3 * N + i], SCAP);
    int d4 = min(cnt[4 * N + i], SCAP);
    int d5 = min(cnt[5 * N + i], SCAP);
    int d6 = min(cnt[6 * N + i], SCAP);
    int d7 = min(cnt[7 * N + i], SCAP);
    int p1 = d0, p2 = p1 + d1, p3 = p2 + d2, p4 = p3 + d3;
    int p5 = p4 + d4, p6 = p5 + d5, p7 = p6 + d6;
    int tot = p7 + d7;
    int deg = __builtin_amdgcn_readfirstlane(min(tot, 64));

    int kk = lane;
    int seg = (kk >= p1) + (kk >= p2) + (kk >= p3) + (kk >= p4)
            + (kk >= p5) + (kk >= p6) + (kk >= p7);
    int bs = 0;
    bs = (seg >= 1) ? p1 : bs;  bs = (seg >= 2) ? p2 : bs;
    bs = (seg >= 3) ? p3 : bs;  bs = (seg >= 4) ? p4 : bs;
    bs = (seg >= 5) ? p5 : bs;  bs = (seg >= 6) ? p6 : bs;
    bs = (seg >= 7) ? p7 : bs;
    int off = (kk - bs) & (SCAP - 1);

    EdgeRec er;
    er.u = bucket[((seg * N + i) << 4) + off];
    bool valid = lane < deg;

    float dx = (float)er.h[0];
    float dy = (float)er.h[1];
    float dz = (float)er.h[2];
    int tj = er.s[3];

    float u  = fmaf(dz, dz, fmaf(dy, dy, fmaf(dx, dx, 1e-12f)));
    float wv = __log2f(u);
    float ir = rsqrtf(u);
    float iu = ir * ir;
    float lf = 0.0f;
    if (u >= 10.89f) {                       // 3.3 <= r: taper folded into exp
        float r = sqrtf(u);
        float fcv = 0.5f + 0.5f * __cosf(10.471975511965978f * (r - 3.3f));
        lf = __log2f(fmaxf(fcv, 1e-30f));    // clamp: f16-rounded u can cross 3.6
    }

    // 12 radials R_n = exp2(0.5n*log2(u) + qc_n*u + lf)
    const float QC[12] = {
        -8.014972449383130f, -8.014972449383130f, -4.007486224691565f,
        -2.671657483127710f, -2.003743112345783f, -1.602994489876626f,
        -1.335828741563855f, -1.144996064197590f, -1.001871556172891f,
        -0.890552494375903f, -0.801497244938313f, -0.728633859034830f };
    float R[12];
    #pragma unroll
    for (int n = 0; n < 12; ++n)
        R[n] = exp2_fast(fmaf(0.5f * n, wv, fmaf(QC[n], u, lf)));

    // type-sort among valid lanes
    ull m0b = __ballot(valid && tj == 0);
    ull m1b = __ballot(valid && tj == 1);
    ull m2b = __ballot(valid && tj == 2);
    ull lt  = (lane == 63) ? 0x7FFFFFFFFFFFFFFFull : ((1ull << lane) - 1ull);
    int c0n = __popcll(m0b);
    int c1n = __popcll(m1b);
    int dest;
    if (!valid)          dest = deg + __popcll(~(m0b | m1b | m2b) & lt);
    else if (tj == 0)    dest = __popcll(m0b & lt);
    else if (tj == 1)    dest = c0n + __popcll(m1b & lt);
    else                 dest = c0n + c1n + __popcll(m2b & lt);

    float* rec = &sE[wslot][dest][0];
    #pragma unroll
    for (int n = 0; n < 12; ++n) rec[n] = R[n];
    rec[12] = 1.0f;
    rec[13] = dy * ir;  rec[14] = dz * ir;  rec[15] = dx * ir;
    rec[16] = dx * dy * iu;
    rec[17] = dy * dz * iu;
    rec[18] = fmaf(dz, dz, -0.33333333333333333f * u) * iu;
    rec[19] = dx * dz * iu;
    rec[20] = fmaf(dx, dx, -(dy * dy)) * iu;
    asm volatile("s_waitcnt lgkmcnt(0)" ::: "memory");

    int e1b = c0n + c1n;                     // scalar (ballot popcounts)

    // per-lane slot indices: slot0 = lane, slot1 = lane+64 (slot = m*12+n)
    int n0 = lane % 12, m0 = lane / 12;
    int idx1 = lane + 64;
    bool has1 = idx1 < 108;
    int i1 = has1 ? idx1 : 0;
    int n1 = i1 % 12, m1 = i1 / 12;

    const float* recb = &sE[wslot][0][0];

    float a00 = 0.f, a01 = 0.f, a02 = 0.f;
    float a10 = 0.f, a11 = 0.f, a12 = 0.f;

    #define EDGE_BODY(E_IDX, ACC0, ACC1)                                   \
    {                                                                      \
        const float* rp = recb + (E_IDX) * RSTRIDE;                        \
        float Rv0 = rp[n0];                                                \
        float Tv0 = rp[12 + m0];                                           \
        float Rv1 = rp[n1];                                                \
        float Tv1 = rp[12 + m1];                                           \
        ACC0 = fmaf(Rv0, Tv0, ACC0);                                       \
        ACC1 = fmaf(Rv1, Tv1, ACC1);                                       \
    }

    int e = 0;
    #pragma unroll 4
    for (; e < c0n; ++e)  EDGE_BODY(e, a00, a10);
    #pragma unroll 4
    for (; e < e1b; ++e)  EDGE_BODY(e, a01, a11);
    #pragma unroll 4
    for (; e < deg; ++e)  EDGE_BODY(e, a02, a12);
    #undef EDGE_BODY

    __hip_bfloat16* cb = c2 + (size_t)i * CPA;
    cb[m0 * 36 + 0 * 12 + n0] = __float2bfloat16(a00);
    cb[m0 * 36 + 1 * 12 + n0] = __float2bfloat16(a01);
    cb[m0 * 36 + 2 * 12 + n0] = __float2bfloat16(a02);
    if (has1) {
        cb[m1 * 36 + 0 * 12 + n1] = __float2bfloat16(a10);
        cb[m1 * 36 + 1 * 12 + n1] = __float2bfloat16(a11);
        cb[m1 * 36 + 2 * 12 + n1] = __float2bfloat16(a12);
    }
}

// Wave = (64 atoms, one m). Block q = tile q -> XCD q%8 (matches accum).
__global__ void __launch_bounds__(576)
quad_kernel(const __hip_bfloat16* __restrict__ c2,
            const int* __restrict__ types,
            const float* __restrict__ A,
            float* __restrict__ out, int N) {
    __shared__ float sred[9];
    int m = __builtin_amdgcn_readfirstlane(threadIdx.x >> 6);
    int lane = threadIdx.x & 63;
    int i = blockIdx.x * 64 + lane;
    float dot = 0.0f;
    if (i < N) {
        float Km = m == 0 ? 0.28209479177387814f
                 : (m < 4 ? 0.4886025119029199f
                 : (m == 6 ? 0.94617469575756f
                 : (m == 8 ? 0.5462742152960396f : 1.0925484305920792f)));
        const ushort4v* cb4 =
            (const ushort4v*)(c2 + (size_t)i * CPA + m * 36);
        float v[36];
        #pragma unroll
        for (int q = 0; q < 9; ++q) {
            ushort4v u = cb4[q];
            #pragma unroll
            for (int r = 0; r < 4; ++r)
                v[q * 4 + r] = __uint_as_float(((unsigned)u[r]) << 16) * Km;
        }
        if (m == 0) {
            int ti = types[i];
            const float Y00 = 0.28209479177387814f;
            v[0]  += ti == 0 ? Y00 : 0.f;
            v[12] += ti == 1 ? Y00 : 0.f;
            v[24] += ti == 2 ? Y00 : 0.f;
        }
        int l = (m == 0) ? 0 : (m < 4 ? 1 : 2);
        const float* Al = A + l * 1296;
        #pragma unroll
        for (int an = 0; an < 36; ++an) {
            float s = 0.0f;
            #pragma unroll
            for (int b = 0; b < 36; ++b)
                s = fmaf(Al[an * 36 + b], v[b], s);
            dot = fmaf(v[an], s, dot);
        }
    }
    #pragma unroll
    for (int off = 32; off > 0; off >>= 1) dot += __shfl_down(dot, off, 64);
    if (lane == 0) sred[m] = dot;
    __syncthreads();
    if (threadIdx.x == 0) {
        float s = 0.f;
        #pragma unroll
        for (int kk = 0; kk < 9; ++kk) s += sred[kk];
        atomicAdd(out, s);
    }
}

extern "C" void kernel_launch(void* const* d_in, const int* in_sizes, int n_in,
                              void* d_out, int out_size, void* d_ws, size_t ws_size,
                              hipStream_t stream) {
    const float* pos   = (const float*)d_in[0];
    const float* w     = (const float*)d_in[1];
    const float* bias  = (const float*)d_in[2];
    const int*   types = (const int*)d_in[3];
    const int*   pairs = (const int*)d_in[4];
    float* out = (float*)d_out;

    int N = in_sizes[0] / 3;
    int E = in_sizes[4] / 2;

    char* ws = (char*)d_ws;
    size_t off = 0;
    float* A = (float*)(ws + off);             off += 16384;
    int* cnt = (int*)(ws + off);               off += ((size_t)N * 32 + 255) & ~(size_t)255;   // 8N ints
    float4* posT = (float4*)(ws + off);        off += ((size_t)N * 16 + 255) & ~(size_t)255;
    uint2* bucket = (uint2*)(ws + off);
                                               off += ((size_t)N * 8 * SCAP * 8 + 255) & ~(size_t)255;
    __hip_bfloat16* c2 = (__hip_bfloat16*)(ws + off);

    int pblocks = (8 * N + 255) / 256;
    prep_kernel<<<pblocks, 256, 0, stream>>>(w, bias, pos, types, A, posT, cnt, out, N);

    int equads = (E + 3) / 4;
    int eblocks = (equads + 255) / 256;
    build_kernel<<<eblocks, 256, 0, stream>>>(pairs, posT, cnt, bucket, E, N);

    int T = (N + 63) / 64;                    // 64-atom tiles
    int perXCD = (T + 7) / 8;
    int ablocks = perXCD * 8 * 16;            // 16 blocks (4 atoms each) per tile
    accum_kernel<<<ablocks, 256, 0, stream>>>(cnt, bucket, c2, N, T);

    int qblocks = T;
    quad_kernel<<<qblocks, 576, 0, stream>>>(c2, types, A, out, N);
}